// Round 3
// baseline (358.015 us; speedup 1.0000x reference)
//
#include <hip/hip_runtime.h>
#include <math.h>

#define HALO 10
#define TS 32
#define LSTR 46   // LDS row stride (words): keeps writes at free 2-way bank aliasing, b64-aligned

struct GaussW { float g[11]; };

__global__ void init_acc_kernel(float* acc) {
    int i = threadIdx.x;
    if (i < 128) acc[i] = 0.f;
}

template <int H, bool DO_POOL>
__global__ __launch_bounds__(256, 5) void ssim_level_kernel(
    const float* __restrict__ X, const float* __restrict__ Y,
    GaussW gw, float* __restrict__ sum_out,
    float* __restrict__ Xpool, float* __restrict__ Ypool)
{
    constexpr int W = H;
    constexpr int Hout = H - HALO;
    constexpr int Wout = W - HALO;

    // Transposed blurred-quantity tiles: [quantity][out_col][in_row]
    // Q0: blur(x)  Q1: blur(y)  Q2: blur((x+y)^2)  Q3: blur((x-y)^2)
    __shared__ float Hs[4][TS][LSTR];
    __shared__ float red[4];

    const int tid = threadIdx.x;
    const int bc  = blockIdx.z;        // b*3 + c
    const int b   = bc / 3;
    const int r0  = blockIdx.y * TS;
    const int c0  = blockIdx.x * TS;
    const size_t base = (size_t)bc * H * W;

    // ---- Phase A: horizontal 11-tap blur, direct from global ----
    // 42 rows x 4 segments of 8 output cols = 168 threads
    if (tid < 168) {
        const int rr  = tid >> 2;
        const int seg = tid & 3;
        const int gr  = r0 + rr;
        const int gc0 = c0 + seg * 8;
        const bool rowok = (gr < H);

        float x[20], y[20];
        if (rowok && (gc0 + 20 <= W)) {
            const float* xp = X + base + (size_t)gr * W + gc0;
            const float* yp = Y + base + (size_t)gr * W + gc0;
            #pragma unroll
            for (int v = 0; v < 5; ++v) {
                float4 xv = *(const float4*)(xp + 4 * v);
                float4 yv = *(const float4*)(yp + 4 * v);
                x[4*v+0] = xv.x; x[4*v+1] = xv.y; x[4*v+2] = xv.z; x[4*v+3] = xv.w;
                y[4*v+0] = yv.x; y[4*v+1] = yv.y; y[4*v+2] = yv.z; y[4*v+3] = yv.w;
            }
        } else {
            const int grc = rowok ? gr : (H - 1);
            const float* xp = X + base + (size_t)grc * W;
            const float* yp = Y + base + (size_t)grc * W;
            #pragma unroll
            for (int i = 0; i < 20; ++i) {
                int gc  = gc0 + i;
                int gcc = gc < W ? gc : (W - 1);
                bool ok = rowok && (gc < W);
                float xv = xp[gcc], yv = yp[gcc];
                x[i] = ok ? xv : 0.f;
                y[i] = ok ? yv : 0.f;
            }
        }

        const int ccb = seg * 8;
        // linear terms
        #pragma unroll
        for (int j = 0; j < 8; ++j) {
            float s = 0.f;
            #pragma unroll
            for (int k = 0; k < 11; ++k) s = fmaf(gw.g[k], x[j + k], s);
            Hs[0][ccb + j][rr] = s;
        }
        #pragma unroll
        for (int j = 0; j < 8; ++j) {
            float s = 0.f;
            #pragma unroll
            for (int k = 0; k < 11; ++k) s = fmaf(gw.g[k], y[j + k], s);
            Hs[1][ccb + j][rr] = s;
        }
        // in-place: x := (x+y)^2, y := (x-y)^2  (only [0..17] feed the blurs)
        #pragma unroll
        for (int i = 0; i < 18; ++i) {
            float a = x[i] + y[i];
            float d = x[i] - y[i];
            x[i] = a * a;
            y[i] = d * d;
        }
        #pragma unroll
        for (int j = 0; j < 8; ++j) {
            float s = 0.f;
            #pragma unroll
            for (int k = 0; k < 11; ++k) s = fmaf(gw.g[k], x[j + k], s);
            Hs[2][ccb + j][rr] = s;
        }
        #pragma unroll
        for (int j = 0; j < 8; ++j) {
            float s = 0.f;
            #pragma unroll
            for (int k = 0; k < 11; ++k) s = fmaf(gw.g[k], y[j + k], s);
            Hs[3][ccb + j][rr] = s;
        }
    }
    __syncthreads();

    // ---- Phase C: vertical 11-tap blur (b64 contiguous reads) + SSIM math ----
    const int tx = tid & 31;     // output col
    const int ty = tid >> 5;     // 0..7, owns 4 consecutive output rows
    const int rb = ty * 4;

    float m1[4], m2[4], S[4], D[4];
    #define VPASS(Q, OUT)                                                        \
    {                                                                            \
        float win[14];                                                           \
        _Pragma("unroll")                                                        \
        for (int i = 0; i < 7; ++i)                                              \
            *(float2*)&win[2 * i] = *(const float2*)&Hs[Q][tx][rb + 2 * i];      \
        _Pragma("unroll")                                                        \
        for (int o = 0; o < 4; ++o) {                                            \
            float s = 0.f;                                                       \
            _Pragma("unroll")                                                    \
            for (int k = 0; k < 11; ++k) s = fmaf(gw.g[k], win[o + k], s);       \
            OUT[o] = s;                                                          \
        }                                                                        \
    }
    VPASS(0, m1) VPASS(1, m2) VPASS(2, S) VPASS(3, D)
    #undef VPASS

    const float C1 = 1e-4f, C2 = 9e-4f;
    float acc_s = 0.f;
    #pragma unroll
    for (int o = 0; o < 4; ++o) {
        float u1 = m1[o], u2 = m2[o];
        float u1s = u1 * u1, u2s = u2 * u2, u12 = u1 * u2;
        float ssum = 0.5f  * (S[o] + D[o]);     // blur(xx) + blur(yy)
        float sxy  = 0.25f * (S[o] - D[o]);     // blur(xy)
        float vsum = ssum - u1s - u2s;          // v1 + v2
        float v12  = sxy - u12;
        float A2   = fmaxf(2.f * v12 + C2, 0.f);
        float B1   = u1s + u2s + C1;
        float B2   = vsum + C2;
        float inv  = __builtin_amdgcn_rcpf(B1 * B2);
        float val;
        if (DO_POOL) {                 // levels 0-2: cs = A2/B2
            val = A2 * B1 * inv;
        } else {                       // level 3: ss = A1*A2/(B1*B2)
            float A1 = 2.f * u12 + C1;
            val = A1 * A2 * inv;
        }
        bool valid = (r0 + rb + o < Hout) && (c0 + tx < Wout);
        acc_s += valid ? val : 0.f;
    }

    // ---- Phase D: fused 2x2 avg-pool of this block's 32x32 input region ----
    if (DO_POOL) {
        constexpr int Wp = W / 2;
        const int pr = tid >> 4, pc = tid & 15;
        const size_t srow = base + (size_t)(r0 + 2 * pr) * W + (c0 + 2 * pc);
        float2 xa = *(const float2*)(X + srow);
        float2 xb = *(const float2*)(X + srow + W);
        float2 ya = *(const float2*)(Y + srow);
        float2 yb = *(const float2*)(Y + srow + W);
        const size_t o = (size_t)bc * (H / 2) * Wp + (size_t)(r0 / 2 + pr) * Wp + (c0 / 2 + pc);
        Xpool[o] = 0.25f * (xa.x + xa.y + xb.x + xb.y);
        Ypool[o] = 0.25f * (ya.x + ya.y + yb.x + yb.y);
    }

    // ---- Phase E: block reduction + one atomic ----
    #pragma unroll
    for (int off = 32; off; off >>= 1) acc_s += __shfl_down(acc_s, off);
    if ((tid & 63) == 0) red[tid >> 6] = acc_s;
    __syncthreads();
    if (tid == 0) atomicAdd(&sum_out[b], red[0] + red[1] + red[2] + red[3]);
}

__global__ void finalize_kernel(const float* __restrict__ acc, float* __restrict__ out) {
    int b = threadIdx.x;
    if (b >= 16) return;
    const float wraw[4] = {0.0448f, 0.2856f, 0.3001f, 0.2363f};
    float wsum = wraw[0] + wraw[1] + wraw[2] + wraw[3];
    float ms = 1.f;
    for (int l = 0; l < 4; ++l) {
        int H = 512 >> l;
        int Hout = H - HALO;
        float cnt = 3.f * (float)Hout * (float)Hout;
        float val = (l < 3 ? acc[l * 16 + b] : acc[64 + l * 16 + b]) / cnt;
        val = fmaxf(val, 1e-8f);
        ms *= powf(val, wraw[l] / wsum);
    }
    out[b] = 1.f - ms;
}

extern "C" void kernel_launch(void* const* d_in, const int* in_sizes, int n_in,
                              void* d_out, int out_size, void* d_ws, size_t ws_size,
                              hipStream_t stream)
{
    const float* X0 = (const float*)d_in[0];
    const float* Y0 = (const float*)d_in[1];
    float* out = (float*)d_out;
    float* ws  = (float*)d_ws;

    // ws layout (floats): acc[128] | X1 | Y1 | X2 | Y2 | X3 | Y3
    float* acc = ws;
    float* X1 = ws + 128;
    float* Y1 = X1 + (size_t)16 * 3 * 256 * 256;
    float* X2 = Y1 + (size_t)16 * 3 * 256 * 256;
    float* Y2 = X2 + (size_t)16 * 3 * 128 * 128;
    float* X3 = Y2 + (size_t)16 * 3 * 128 * 128;
    float* Y3 = X3 + (size_t)16 * 3 * 64 * 64;

    GaussW gw;
    {
        float s = 0.f;
        for (int i = 0; i < 11; ++i) {
            float d = (float)(i - 5);
            gw.g[i] = expf(-d * d / (2.f * 1.5f * 1.5f));
            s += gw.g[i];
        }
        for (int i = 0; i < 11; ++i) gw.g[i] /= s;
    }

    hipLaunchKernelGGL(init_acc_kernel, dim3(1), dim3(128), 0, stream, acc);

    // levels 0-2 accumulate cs into acc[l*16 + b]; level 3 accumulates ss into acc[112 + b]
    hipLaunchKernelGGL((ssim_level_kernel<512, true>),  dim3(16, 16, 48), dim3(256), 0, stream,
                       X0, Y0, gw, acc + 0,   X1, Y1);
    hipLaunchKernelGGL((ssim_level_kernel<256, true>),  dim3(8, 8, 48),   dim3(256), 0, stream,
                       X1, Y1, gw, acc + 16,  X2, Y2);
    hipLaunchKernelGGL((ssim_level_kernel<128, true>),  dim3(4, 4, 48),   dim3(256), 0, stream,
                       X2, Y2, gw, acc + 32,  X3, Y3);
    hipLaunchKernelGGL((ssim_level_kernel<64, false>),  dim3(2, 2, 48),   dim3(256), 0, stream,
                       X3, Y3, gw, acc + 112, (float*)nullptr, (float*)nullptr);

    hipLaunchKernelGGL(finalize_kernel, dim3(1), dim3(16), 0, stream, acc, out);
}

// Round 4
// 334.064 us; speedup vs baseline: 1.0717x; 1.0717x over previous
//
#include <hip/hip_runtime.h>
#include <math.h>

#define HALO 10
#define TS 32
#define IN 42      // TS + HALO rows staged
#define NP 22      // float2 pairs staged per row (44 cols)
#define XSTR 46    // LDS row stride (words) for Xs/Ys: even (b64 ok), 2-way bank aliasing only
#define HSTR 46    // LDS row stride (words) for Hs (transposed): 14*tx mod 32 has period 16 -> 2-way only

struct GaussW { float g[11]; };

__global__ void init_acc_kernel(float* acc) {
    if (threadIdx.x < 128) acc[threadIdx.x] = 0.f;
}

__global__ __launch_bounds__(256, 4) void ssim_level_kernel(
    const float* __restrict__ X, const float* __restrict__ Y,
    int H, GaussW gw, float* __restrict__ sum_out, int last_level,
    float* __restrict__ Xpool, float* __restrict__ Ypool)
{
    const int W = H;
    const int Hout = H - HALO;   // == Wout (square)

    __shared__ float Xs[IN][XSTR];
    __shared__ float Ys[IN][XSTR];
    __shared__ float Hs[4][TS][HSTR];
    __shared__ float red[4];

    const int tid = threadIdx.x;
    const int bc  = blockIdx.z;          // b*3 + c
    const int b   = bc / 3;
    const int r0  = blockIdx.y * TS;
    const int c0  = blockIdx.x * TS;
    const size_t base = (size_t)bc * H * W;

    // ---- Phase 1: coalesced staging of raw tiles (each element fetched once) ----
    // 42 rows x 22 float2 = 924 items; consecutive lanes -> consecutive 8B in a row.
    for (int idx = tid; idx < IN * NP; idx += 256) {
        int rr = idx / NP, pp = idx - rr * NP;
        int gr = r0 + rr, gc = c0 + 2 * pp;
        float2 xv = make_float2(0.f, 0.f), yv = make_float2(0.f, 0.f);
        if (gr < H && gc < W) {          // gc even, W even => gc+1 < W too
            const float* xp = X + base + (size_t)gr * W + gc;
            const float* yp = Y + base + (size_t)gr * W + gc;
            xv = *(const float2*)xp;
            yv = *(const float2*)yp;
        }
        *(float2*)&Xs[rr][2 * pp] = xv;
        *(float2*)&Ys[rr][2 * pp] = yv;
    }
    __syncthreads();

    // ---- Phase 2 (waves 0-2): horizontal 11-tap blur of {x, y, (x+y)^2, (x-y)^2} ----
    // 42 rows x 4 segments of 8 output cols = 168 threads; windows read from LDS (b64).
    if (tid < 168) {
        const int rr  = tid >> 2;
        const int seg = tid & 3;
        const int ccb = seg * 8;

        float x[20], y[20];
        #pragma unroll
        for (int u = 0; u < 10; ++u) {
            *(float2*)&x[2 * u] = *(const float2*)&Xs[rr][ccb + 2 * u];
            *(float2*)&y[2 * u] = *(const float2*)&Ys[rr][ccb + 2 * u];
        }

        #pragma unroll
        for (int j = 0; j < 8; ++j) {
            float s = 0.f;
            #pragma unroll
            for (int k = 0; k < 11; ++k) s = fmaf(gw.g[k], x[j + k], s);
            Hs[0][ccb + j][rr] = s;
        }
        #pragma unroll
        for (int j = 0; j < 8; ++j) {
            float s = 0.f;
            #pragma unroll
            for (int k = 0; k < 11; ++k) s = fmaf(gw.g[k], y[j + k], s);
            Hs[1][ccb + j][rr] = s;
        }
        // in-place: x := (x+y)^2, y := (x-y)^2 (only [0..17] feed the blurs)
        #pragma unroll
        for (int i = 0; i < 18; ++i) {
            float a = x[i] + y[i];
            float d = x[i] - y[i];
            x[i] = a * a;
            y[i] = d * d;
        }
        #pragma unroll
        for (int j = 0; j < 8; ++j) {
            float s = 0.f;
            #pragma unroll
            for (int k = 0; k < 11; ++k) s = fmaf(gw.g[k], x[j + k], s);
            Hs[2][ccb + j][rr] = s;
        }
        #pragma unroll
        for (int j = 0; j < 8; ++j) {
            float s = 0.f;
            #pragma unroll
            for (int k = 0; k < 11; ++k) s = fmaf(gw.g[k], y[j + k], s);
            Hs[3][ccb + j][rr] = s;
        }
    } else if (tid >= 192 && !last_level) {
        // ---- Phase 2 (wave 3): 2x2 avg-pool straight from the LDS tile ----
        const int t = tid - 192;
        const int Wp = W >> 1;
        #pragma unroll
        for (int q = 0; q < 4; ++q) {
            int cell = q * 64 + t;           // 0..255 -> 16x16 pool cells
            int pr = cell >> 4, pc = cell & 15;
            float2 xa = *(const float2*)&Xs[2 * pr][2 * pc];
            float2 xb = *(const float2*)&Xs[2 * pr + 1][2 * pc];
            float2 ya = *(const float2*)&Ys[2 * pr][2 * pc];
            float2 yb = *(const float2*)&Ys[2 * pr + 1][2 * pc];
            size_t o = (size_t)bc * (H >> 1) * Wp + (size_t)(r0 / 2 + pr) * Wp + (c0 / 2 + pc);
            Xpool[o] = 0.25f * (xa.x + xa.y + xb.x + xb.y);
            Ypool[o] = 0.25f * (ya.x + ya.y + yb.x + yb.y);
        }
    }
    __syncthreads();

    // ---- Phase 3: vertical 11-tap blur (contiguous b64 reads) + SSIM math ----
    const int tx = tid & 31;     // output col
    const int ty = tid >> 5;     // 0..7, owns 4 consecutive output rows
    const int rb = ty * 4;

    float m1[4], m2[4], S[4], D[4];
    #define VPASS(Q, OUT)                                                        \
    {                                                                            \
        float win[14];                                                           \
        _Pragma("unroll")                                                        \
        for (int i = 0; i < 7; ++i)                                              \
            *(float2*)&win[2 * i] = *(const float2*)&Hs[Q][tx][rb + 2 * i];      \
        _Pragma("unroll")                                                        \
        for (int o = 0; o < 4; ++o) {                                            \
            float s = 0.f;                                                       \
            _Pragma("unroll")                                                    \
            for (int k = 0; k < 11; ++k) s = fmaf(gw.g[k], win[o + k], s);       \
            OUT[o] = s;                                                          \
        }                                                                        \
    }
    VPASS(0, m1) VPASS(1, m2) VPASS(2, S) VPASS(3, D)
    #undef VPASS

    const float C1 = 1e-4f, C2 = 9e-4f;
    float acc_s = 0.f;
    #pragma unroll
    for (int o = 0; o < 4; ++o) {
        float u1 = m1[o], u2 = m2[o];
        float u1s = u1 * u1, u2s = u2 * u2, u12 = u1 * u2;
        float ssum = 0.5f  * (S[o] + D[o]);     // blur(xx)+blur(yy)
        float sxy  = 0.25f * (S[o] - D[o]);     // blur(xy)
        float vsum = ssum - u1s - u2s;          // v1+v2
        float v12  = sxy - u12;
        float A2   = fmaxf(2.f * v12 + C2, 0.f);
        float B1   = u1s + u2s + C1;
        float B2   = vsum + C2;
        float inv  = __builtin_amdgcn_rcpf(B1 * B2);
        float val;
        if (!last_level) {             // levels 0-2: cs = A2/B2
            val = A2 * B1 * inv;
        } else {                       // level 3: ss = A1*A2/(B1*B2)
            float A1 = 2.f * u12 + C1;
            val = A1 * A2 * inv;
        }
        bool valid = (r0 + rb + o < Hout) && (c0 + tx < Hout);
        acc_s += valid ? val : 0.f;
    }

    // ---- Phase 4: block reduction + one atomic ----
    #pragma unroll
    for (int off = 32; off; off >>= 1) acc_s += __shfl_down(acc_s, off);
    if ((tid & 63) == 0) red[tid >> 6] = acc_s;
    __syncthreads();
    if (tid == 0) atomicAdd(&sum_out[b], red[0] + red[1] + red[2] + red[3]);
}

__global__ void finalize_kernel(const float* __restrict__ acc, float* __restrict__ out) {
    int b = threadIdx.x;
    if (b >= 16) return;
    const float wraw[4] = {0.0448f, 0.2856f, 0.3001f, 0.2363f};
    float wsum = wraw[0] + wraw[1] + wraw[2] + wraw[3];
    float ms = 1.f;
    for (int l = 0; l < 4; ++l) {
        int H = 512 >> l;
        int Hout = H - HALO;
        float cnt = 3.f * (float)Hout * (float)Hout;
        float val = acc[l * 16 + b] / cnt;
        val = fmaxf(val, 1e-8f);
        ms *= powf(val, wraw[l] / wsum);
    }
    out[b] = 1.f - ms;
}

extern "C" void kernel_launch(void* const* d_in, const int* in_sizes, int n_in,
                              void* d_out, int out_size, void* d_ws, size_t ws_size,
                              hipStream_t stream)
{
    const float* X0 = (const float*)d_in[0];
    const float* Y0 = (const float*)d_in[1];
    float* out = (float*)d_out;
    float* ws  = (float*)d_ws;

    // ws layout (floats): acc[128] | X1 | Y1 | X2 | Y2 | X3 | Y3
    float* acc = ws;
    float* X1 = ws + 128;
    float* Y1 = X1 + (size_t)16 * 3 * 256 * 256;
    float* X2 = Y1 + (size_t)16 * 3 * 256 * 256;
    float* Y2 = X2 + (size_t)16 * 3 * 128 * 128;
    float* X3 = Y2 + (size_t)16 * 3 * 128 * 128;
    float* Y3 = X3 + (size_t)16 * 3 * 64 * 64;

    GaussW gw;
    {
        float s = 0.f;
        for (int i = 0; i < 11; ++i) {
            float d = (float)(i - 5);
            gw.g[i] = expf(-d * d / (2.f * 1.5f * 1.5f));
            s += gw.g[i];
        }
        for (int i = 0; i < 11; ++i) gw.g[i] /= s;
    }

    hipLaunchKernelGGL(init_acc_kernel, dim3(1), dim3(128), 0, stream, acc);

    // levels 0-2 accumulate cs into acc[l*16+b]; level 3 accumulates ss into acc[48+b... l*16+b]
    hipLaunchKernelGGL(ssim_level_kernel, dim3(16, 16, 48), dim3(256), 0, stream,
                       X0, Y0, 512, gw, acc + 0,  0, X1, Y1);
    hipLaunchKernelGGL(ssim_level_kernel, dim3(8, 8, 48),   dim3(256), 0, stream,
                       X1, Y1, 256, gw, acc + 16, 0, X2, Y2);
    hipLaunchKernelGGL(ssim_level_kernel, dim3(4, 4, 48),   dim3(256), 0, stream,
                       X2, Y2, 128, gw, acc + 32, 0, X3, Y3);
    hipLaunchKernelGGL(ssim_level_kernel, dim3(2, 2, 48),   dim3(256), 0, stream,
                       X3, Y3, 64,  gw, acc + 48, 1, (float*)nullptr, (float*)nullptr);

    hipLaunchKernelGGL(finalize_kernel, dim3(1), dim3(16), 0, stream, acc, out);
}

// Round 5
// 216.417 us; speedup vs baseline: 1.6543x; 1.5436x over previous
//
#include <hip/hip_runtime.h>
#include <math.h>

#define HALO 10
#define TS 32
#define IN 42      // TS + HALO rows staged
#define NP 22      // float2 pairs staged per row (44 cols)
#define XSTR 46    // LDS row stride (words) for Xs/Ys: even (b64 ok), 2-way bank aliasing only
#define HSTR 46    // LDS row stride (words) for Hs (transposed)
#define NBIN 256   // atomic spreading: one 64B cache line (16 floats) per bin per level

struct GaussW { float g[11]; };

__global__ void init_acc_kernel(float* P) {
    int i = blockIdx.x * 256 + threadIdx.x;
    if (i < 4 * NBIN * 16) P[i] = 0.f;
}

__global__ __launch_bounds__(256, 4) void ssim_level_kernel(
    const float* __restrict__ X, const float* __restrict__ Y,
    int H, GaussW gw, float* __restrict__ Plevel, int last_level,
    float* __restrict__ Xpool, float* __restrict__ Ypool)
{
    const int W = H;
    const int Hout = H - HALO;   // == Wout (square)

    __shared__ float Xs[IN][XSTR];
    __shared__ float Ys[IN][XSTR];
    __shared__ float Hs[4][TS][HSTR];
    __shared__ float red[4];

    const int tid = threadIdx.x;
    const int bc  = blockIdx.z;          // b*3 + c
    const int b   = bc / 3;
    const int r0  = blockIdx.y * TS;
    const int c0  = blockIdx.x * TS;
    const size_t base = (size_t)bc * H * W;

    // ---- Phase 1: coalesced staging of raw tiles (each element fetched once) ----
    for (int idx = tid; idx < IN * NP; idx += 256) {
        int rr = idx / NP, pp = idx - rr * NP;
        int gr = r0 + rr, gc = c0 + 2 * pp;
        float2 xv = make_float2(0.f, 0.f), yv = make_float2(0.f, 0.f);
        if (gr < H && gc < W) {          // gc even, W even => gc+1 < W too
            const float* xp = X + base + (size_t)gr * W + gc;
            const float* yp = Y + base + (size_t)gr * W + gc;
            xv = *(const float2*)xp;
            yv = *(const float2*)yp;
        }
        *(float2*)&Xs[rr][2 * pp] = xv;
        *(float2*)&Ys[rr][2 * pp] = yv;
    }
    __syncthreads();

    // ---- Phase 2 (waves 0-2): horizontal 11-tap blur of {x, y, (x+y)^2, (x-y)^2} ----
    if (tid < 168) {
        const int rr  = tid >> 2;
        const int seg = tid & 3;
        const int ccb = seg * 8;

        float x[20], y[20];
        #pragma unroll
        for (int u = 0; u < 10; ++u) {
            *(float2*)&x[2 * u] = *(const float2*)&Xs[rr][ccb + 2 * u];
            *(float2*)&y[2 * u] = *(const float2*)&Ys[rr][ccb + 2 * u];
        }

        #pragma unroll
        for (int j = 0; j < 8; ++j) {
            float s = 0.f;
            #pragma unroll
            for (int k = 0; k < 11; ++k) s = fmaf(gw.g[k], x[j + k], s);
            Hs[0][ccb + j][rr] = s;
        }
        #pragma unroll
        for (int j = 0; j < 8; ++j) {
            float s = 0.f;
            #pragma unroll
            for (int k = 0; k < 11; ++k) s = fmaf(gw.g[k], y[j + k], s);
            Hs[1][ccb + j][rr] = s;
        }
        #pragma unroll
        for (int i = 0; i < 18; ++i) {
            float a = x[i] + y[i];
            float d = x[i] - y[i];
            x[i] = a * a;
            y[i] = d * d;
        }
        #pragma unroll
        for (int j = 0; j < 8; ++j) {
            float s = 0.f;
            #pragma unroll
            for (int k = 0; k < 11; ++k) s = fmaf(gw.g[k], x[j + k], s);
            Hs[2][ccb + j][rr] = s;
        }
        #pragma unroll
        for (int j = 0; j < 8; ++j) {
            float s = 0.f;
            #pragma unroll
            for (int k = 0; k < 11; ++k) s = fmaf(gw.g[k], y[j + k], s);
            Hs[3][ccb + j][rr] = s;
        }
    } else if (tid >= 192 && !last_level) {
        // ---- Phase 2 (wave 3): 2x2 avg-pool straight from the LDS tile ----
        const int t = tid - 192;
        const int Wp = W >> 1;
        #pragma unroll
        for (int q = 0; q < 4; ++q) {
            int cell = q * 64 + t;           // 0..255 -> 16x16 pool cells
            int pr = cell >> 4, pc = cell & 15;
            float2 xa = *(const float2*)&Xs[2 * pr][2 * pc];
            float2 xb = *(const float2*)&Xs[2 * pr + 1][2 * pc];
            float2 ya = *(const float2*)&Ys[2 * pr][2 * pc];
            float2 yb = *(const float2*)&Ys[2 * pr + 1][2 * pc];
            size_t o = (size_t)bc * (H >> 1) * Wp + (size_t)(r0 / 2 + pr) * Wp + (c0 / 2 + pc);
            Xpool[o] = 0.25f * (xa.x + xa.y + xb.x + xb.y);
            Ypool[o] = 0.25f * (ya.x + ya.y + yb.x + yb.y);
        }
    }
    __syncthreads();

    // ---- Phase 3: vertical 11-tap blur (contiguous b64 reads) + SSIM math ----
    const int tx = tid & 31;     // output col
    const int ty = tid >> 5;     // 0..7, owns 4 consecutive output rows
    const int rb = ty * 4;

    float m1[4], m2[4], S[4], D[4];
    #define VPASS(Q, OUT)                                                        \
    {                                                                            \
        float win[14];                                                           \
        _Pragma("unroll")                                                        \
        for (int i = 0; i < 7; ++i)                                              \
            *(float2*)&win[2 * i] = *(const float2*)&Hs[Q][tx][rb + 2 * i];      \
        _Pragma("unroll")                                                        \
        for (int o = 0; o < 4; ++o) {                                            \
            float s = 0.f;                                                       \
            _Pragma("unroll")                                                    \
            for (int k = 0; k < 11; ++k) s = fmaf(gw.g[k], win[o + k], s);       \
            OUT[o] = s;                                                          \
        }                                                                        \
    }
    VPASS(0, m1) VPASS(1, m2) VPASS(2, S) VPASS(3, D)
    #undef VPASS

    const float C1 = 1e-4f, C2 = 9e-4f;
    float acc_s = 0.f;
    #pragma unroll
    for (int o = 0; o < 4; ++o) {
        float u1 = m1[o], u2 = m2[o];
        float u1s = u1 * u1, u2s = u2 * u2, u12 = u1 * u2;
        float ssum = 0.5f  * (S[o] + D[o]);     // blur(xx)+blur(yy)
        float sxy  = 0.25f * (S[o] - D[o]);     // blur(xy)
        float vsum = ssum - u1s - u2s;          // v1+v2
        float v12  = sxy - u12;
        float A2   = fmaxf(2.f * v12 + C2, 0.f);
        float B1   = u1s + u2s + C1;
        float B2   = vsum + C2;
        float inv  = __builtin_amdgcn_rcpf(B1 * B2);
        float val;
        if (!last_level) {             // levels 0-2: cs = A2/B2
            val = A2 * B1 * inv;
        } else {                       // level 3: ss = A1*A2/(B1*B2)
            float A1 = 2.f * u12 + C1;
            val = A1 * A2 * inv;
        }
        bool valid = (r0 + rb + o < Hout) && (c0 + tx < Hout);
        acc_s += valid ? val : 0.f;
    }

    // ---- Phase 4: block reduction + one atomic into a bin-spread line ----
    #pragma unroll
    for (int off = 32; off; off >>= 1) acc_s += __shfl_down(acc_s, off);
    if ((tid & 63) == 0) red[tid >> 6] = acc_s;
    __syncthreads();
    if (tid == 0) {
        int lin = blockIdx.x + gridDim.x * (blockIdx.y + gridDim.y * blockIdx.z);
        int bin = lin & (NBIN - 1);
        atomicAdd(&Plevel[bin * 16 + b], red[0] + red[1] + red[2] + red[3]);
    }
}

__global__ void finalize_kernel(const float* __restrict__ P, float* __restrict__ out) {
    __shared__ float red[64][4];
    const int tid  = threadIdx.x;      // 256
    const int pair = tid >> 2;         // 0..63 = l*16 + b
    const int chnk = tid & 3;
    const int l = pair >> 4, b = pair & 15;
    float s = 0.f;
    #pragma unroll 4
    for (int j = 0; j < 64; ++j)
        s += P[((l * NBIN) + (chnk * 64) + j) * 16 + b];
    red[pair][chnk] = s;
    __syncthreads();
    if (tid < 16) {
        const int bb = tid;
        const float wraw[4] = {0.0448f, 0.2856f, 0.3001f, 0.2363f};
        float wsum = wraw[0] + wraw[1] + wraw[2] + wraw[3];
        float ms = 1.f;
        for (int ll = 0; ll < 4; ++ll) {
            int Hh = 512 >> ll;
            int Ho = Hh - HALO;
            float cnt = 3.f * (float)Ho * (float)Ho;
            float val = (red[ll * 16 + bb][0] + red[ll * 16 + bb][1] +
                         red[ll * 16 + bb][2] + red[ll * 16 + bb][3]) / cnt;
            val = fmaxf(val, 1e-8f);
            ms *= powf(val, wraw[ll] / wsum);
        }
        out[bb] = 1.f - ms;
    }
}

extern "C" void kernel_launch(void* const* d_in, const int* in_sizes, int n_in,
                              void* d_out, int out_size, void* d_ws, size_t ws_size,
                              hipStream_t stream)
{
    const float* X0 = (const float*)d_in[0];
    const float* Y0 = (const float*)d_in[1];
    float* out = (float*)d_out;
    float* ws  = (float*)d_ws;

    // ws layout (floats): P[4][NBIN][16] | X1 | Y1 | X2 | Y2 | X3 | Y3
    const size_t PSZ = (size_t)4 * NBIN * 16;
    float* P  = ws;
    float* X1 = ws + PSZ;
    float* Y1 = X1 + (size_t)16 * 3 * 256 * 256;
    float* X2 = Y1 + (size_t)16 * 3 * 256 * 256;
    float* Y2 = X2 + (size_t)16 * 3 * 128 * 128;
    float* X3 = Y2 + (size_t)16 * 3 * 128 * 128;
    float* Y3 = X3 + (size_t)16 * 3 * 64 * 64;

    GaussW gw;
    {
        float s = 0.f;
        for (int i = 0; i < 11; ++i) {
            float d = (float)(i - 5);
            gw.g[i] = expf(-d * d / (2.f * 1.5f * 1.5f));
            s += gw.g[i];
        }
        for (int i = 0; i < 11; ++i) gw.g[i] /= s;
    }

    hipLaunchKernelGGL(init_acc_kernel, dim3((4 * NBIN * 16 + 255) / 256), dim3(256), 0, stream, P);

    hipLaunchKernelGGL(ssim_level_kernel, dim3(16, 16, 48), dim3(256), 0, stream,
                       X0, Y0, 512, gw, P + 0 * NBIN * 16, 0, X1, Y1);
    hipLaunchKernelGGL(ssim_level_kernel, dim3(8, 8, 48),   dim3(256), 0, stream,
                       X1, Y1, 256, gw, P + 1 * NBIN * 16, 0, X2, Y2);
    hipLaunchKernelGGL(ssim_level_kernel, dim3(4, 4, 48),   dim3(256), 0, stream,
                       X2, Y2, 128, gw, P + 2 * NBIN * 16, 0, X3, Y3);
    hipLaunchKernelGGL(ssim_level_kernel, dim3(2, 2, 48),   dim3(256), 0, stream,
                       X3, Y3, 64,  gw, P + 3 * NBIN * 16, 1, (float*)nullptr, (float*)nullptr);

    hipLaunchKernelGGL(finalize_kernel, dim3(1), dim3(256), 0, stream, P, out);
}

// Round 6
// 206.774 us; speedup vs baseline: 1.7314x; 1.0466x over previous
//
#include <hip/hip_runtime.h>
#include <math.h>

#define HALO 10
#define TS 32
#define IN 42      // TS + HALO rows staged
#define NP 22      // float2 pairs staged per row (44 cols)
#define XSTR 46    // LDS row stride (words) for Xs/Ys: even (b64 ok), 2-way bank aliasing only
#define HSTR 46    // LDS row stride (words) for Hs (transposed)
#define NBIN 256   // atomic spreading: one 64B cache line (16 floats) per bin per level

typedef float f2 __attribute__((ext_vector_type(2)));

struct GaussW { float g[11]; };

__global__ void init_acc_kernel(float* P) {
    int i = blockIdx.x * 256 + threadIdx.x;
    if (i < 4 * NBIN * 16) P[i] = 0.f;
}

__global__ __launch_bounds__(256, 4) void ssim_level_kernel(
    const float* __restrict__ X, const float* __restrict__ Y,
    int H, GaussW gw, float* __restrict__ Plevel, int last_level,
    float* __restrict__ Xpool, float* __restrict__ Ypool)
{
    const int W = H;
    const int Hout = H - HALO;   // == Wout (square)

    __shared__ float Xs[IN][XSTR];
    __shared__ float Ys[IN][XSTR];
    __shared__ float Hs[4][TS][HSTR];
    __shared__ float red[4];

    const int tid = threadIdx.x;
    const int bc  = blockIdx.z;          // b*3 + c
    const int b   = bc / 3;
    const int r0  = blockIdx.y * TS;
    const int c0  = blockIdx.x * TS;
    const size_t base = (size_t)bc * H * W;

    // ---- Phase 1: coalesced staging of raw tiles (each element fetched once) ----
    for (int idx = tid; idx < IN * NP; idx += 256) {
        int rr = idx / NP, pp = idx - rr * NP;
        int gr = r0 + rr, gc = c0 + 2 * pp;
        float2 xv = make_float2(0.f, 0.f), yv = make_float2(0.f, 0.f);
        if (gr < H && gc < W) {          // gc even, W even => gc+1 < W too
            const float* xp = X + base + (size_t)gr * W + gc;
            const float* yp = Y + base + (size_t)gr * W + gc;
            xv = *(const float2*)xp;
            yv = *(const float2*)yp;
        }
        *(float2*)&Xs[rr][2 * pp] = xv;
        *(float2*)&Ys[rr][2 * pp] = yv;
    }
    __syncthreads();

    // ---- Phase 2 (waves 0-2): horizontal 11-tap blur of {x, y, (x+y)^2, (x-y)^2} ----
    // Two adjacent outputs per f2 accumulator -> v_pk_fma_f32 (packed fp32, 2 FMA/inst).
    if (tid < 168) {
        const int rr  = tid >> 2;
        const int seg = tid & 3;
        const int ccb = seg * 8;

        float x[20], y[20];
        #pragma unroll
        for (int u = 0; u < 10; ++u) {
            *(f2*)&x[2 * u] = *(const f2*)&Xs[rr][ccb + 2 * u];
            *(f2*)&y[2 * u] = *(const f2*)&Ys[rr][ccb + 2 * u];
        }

        #pragma unroll
        for (int p = 0; p < 4; ++p) {
            f2 ax = {0.f, 0.f}, ay = {0.f, 0.f};
            #pragma unroll
            for (int k = 0; k < 11; ++k) {
                f2 vx = { x[2 * p + k], x[2 * p + k + 1] };
                f2 vy = { y[2 * p + k], y[2 * p + k + 1] };
                ax += vx * gw.g[k];
                ay += vy * gw.g[k];
            }
            Hs[0][ccb + 2 * p    ][rr] = ax.x;
            Hs[0][ccb + 2 * p + 1][rr] = ax.y;
            Hs[1][ccb + 2 * p    ][rr] = ay.x;
            Hs[1][ccb + 2 * p + 1][rr] = ay.y;
        }
        // in-place: x := (x+y)^2, y := (x-y)^2 (only [0..17] feed the blurs); packed
        #pragma unroll
        for (int i = 0; i < 9; ++i) {
            f2 xv = *(f2*)&x[2 * i];
            f2 yv = *(f2*)&y[2 * i];
            f2 a = xv + yv;
            f2 d = xv - yv;
            *(f2*)&x[2 * i] = a * a;
            *(f2*)&y[2 * i] = d * d;
        }
        #pragma unroll
        for (int p = 0; p < 4; ++p) {
            f2 as = {0.f, 0.f}, ad = {0.f, 0.f};
            #pragma unroll
            for (int k = 0; k < 11; ++k) {
                f2 vs = { x[2 * p + k], x[2 * p + k + 1] };
                f2 vd = { y[2 * p + k], y[2 * p + k + 1] };
                as += vs * gw.g[k];
                ad += vd * gw.g[k];
            }
            Hs[2][ccb + 2 * p    ][rr] = as.x;
            Hs[2][ccb + 2 * p + 1][rr] = as.y;
            Hs[3][ccb + 2 * p    ][rr] = ad.x;
            Hs[3][ccb + 2 * p + 1][rr] = ad.y;
        }
    } else if (tid >= 192 && !last_level) {
        // ---- Phase 2 (wave 3): 2x2 avg-pool straight from the LDS tile ----
        const int t = tid - 192;
        const int Wp = W >> 1;
        #pragma unroll
        for (int q = 0; q < 4; ++q) {
            int cell = q * 64 + t;           // 0..255 -> 16x16 pool cells
            int pr = cell >> 4, pc = cell & 15;
            float2 xa = *(const float2*)&Xs[2 * pr][2 * pc];
            float2 xb = *(const float2*)&Xs[2 * pr + 1][2 * pc];
            float2 ya = *(const float2*)&Ys[2 * pr][2 * pc];
            float2 yb = *(const float2*)&Ys[2 * pr + 1][2 * pc];
            size_t o = (size_t)bc * (H >> 1) * Wp + (size_t)(r0 / 2 + pr) * Wp + (c0 / 2 + pc);
            Xpool[o] = 0.25f * (xa.x + xa.y + xb.x + xb.y);
            Ypool[o] = 0.25f * (ya.x + ya.y + yb.x + yb.y);
        }
    }
    __syncthreads();

    // ---- Phase 3: vertical 11-tap blur (contiguous b64 reads, packed FMA) + SSIM ----
    const int tx = tid & 31;     // output col
    const int ty = tid >> 5;     // 0..7, owns 4 consecutive output rows
    const int rb = ty * 4;

    f2 m1[2], m2[2], S[2], D[2];
    #define VPASS(Q, OUT)                                                        \
    {                                                                            \
        float win[14];                                                           \
        _Pragma("unroll")                                                        \
        for (int i = 0; i < 7; ++i)                                              \
            *(f2*)&win[2 * i] = *(const f2*)&Hs[Q][tx][rb + 2 * i];              \
        _Pragma("unroll")                                                        \
        for (int h = 0; h < 2; ++h) {                                            \
            f2 acc = {0.f, 0.f};                                                 \
            _Pragma("unroll")                                                    \
            for (int k = 0; k < 11; ++k) {                                       \
                f2 v = { win[2 * h + k], win[2 * h + k + 1] };                   \
                acc += v * gw.g[k];                                              \
            }                                                                    \
            OUT[h] = acc;                                                        \
        }                                                                        \
    }
    VPASS(0, m1) VPASS(1, m2) VPASS(2, S) VPASS(3, D)
    #undef VPASS

    const float C1 = 1e-4f, C2 = 9e-4f;
    float acc_s = 0.f;
    #pragma unroll
    for (int o = 0; o < 4; ++o) {
        float u1 = m1[o >> 1][o & 1], u2 = m2[o >> 1][o & 1];
        float Sv = S[o >> 1][o & 1],  Dv = D[o >> 1][o & 1];
        float u1s = u1 * u1, u2s = u2 * u2, u12 = u1 * u2;
        float ssum = 0.5f  * (Sv + Dv);         // blur(xx)+blur(yy)
        float sxy  = 0.25f * (Sv - Dv);         // blur(xy)
        float vsum = ssum - u1s - u2s;          // v1+v2
        float v12  = sxy - u12;
        float A2   = fmaxf(2.f * v12 + C2, 0.f);
        float B1   = u1s + u2s + C1;
        float B2   = vsum + C2;
        float inv  = __builtin_amdgcn_rcpf(B1 * B2);
        float val;
        if (!last_level) {             // levels 0-2: cs = A2/B2
            val = A2 * B1 * inv;
        } else {                       // level 3: ss = A1*A2/(B1*B2)
            float A1 = 2.f * u12 + C1;
            val = A1 * A2 * inv;
        }
        bool valid = (r0 + rb + o < Hout) && (c0 + tx < Hout);
        acc_s += valid ? val : 0.f;
    }

    // ---- Phase 4: block reduction + one atomic into a bin-spread line ----
    #pragma unroll
    for (int off = 32; off; off >>= 1) acc_s += __shfl_down(acc_s, off);
    if ((tid & 63) == 0) red[tid >> 6] = acc_s;
    __syncthreads();
    if (tid == 0) {
        int lin = blockIdx.x + gridDim.x * (blockIdx.y + gridDim.y * blockIdx.z);
        int bin = lin & (NBIN - 1);
        atomicAdd(&Plevel[bin * 16 + b], red[0] + red[1] + red[2] + red[3]);
    }
}

__global__ void finalize_kernel(const float* __restrict__ P, float* __restrict__ out) {
    __shared__ float red[64][4];
    const int tid  = threadIdx.x;      // 256
    const int pair = tid >> 2;         // 0..63 = l*16 + b
    const int chnk = tid & 3;
    const int l = pair >> 4, b = pair & 15;
    float s = 0.f;
    #pragma unroll 4
    for (int j = 0; j < 64; ++j)
        s += P[((l * NBIN) + (chnk * 64) + j) * 16 + b];
    red[pair][chnk] = s;
    __syncthreads();
    if (tid < 16) {
        const int bb = tid;
        const float wraw[4] = {0.0448f, 0.2856f, 0.3001f, 0.2363f};
        float wsum = wraw[0] + wraw[1] + wraw[2] + wraw[3];
        float ms = 1.f;
        for (int ll = 0; ll < 4; ++ll) {
            int Hh = 512 >> ll;
            int Ho = Hh - HALO;
            float cnt = 3.f * (float)Ho * (float)Ho;
            float val = (red[ll * 16 + bb][0] + red[ll * 16 + bb][1] +
                         red[ll * 16 + bb][2] + red[ll * 16 + bb][3]) / cnt;
            val = fmaxf(val, 1e-8f);
            ms *= powf(val, wraw[ll] / wsum);
        }
        out[bb] = 1.f - ms;
    }
}

extern "C" void kernel_launch(void* const* d_in, const int* in_sizes, int n_in,
                              void* d_out, int out_size, void* d_ws, size_t ws_size,
                              hipStream_t stream)
{
    const float* X0 = (const float*)d_in[0];
    const float* Y0 = (const float*)d_in[1];
    float* out = (float*)d_out;
    float* ws  = (float*)d_ws;

    // ws layout (floats): P[4][NBIN][16] | X1 | Y1 | X2 | Y2 | X3 | Y3
    const size_t PSZ = (size_t)4 * NBIN * 16;
    float* P  = ws;
    float* X1 = ws + PSZ;
    float* Y1 = X1 + (size_t)16 * 3 * 256 * 256;
    float* X2 = Y1 + (size_t)16 * 3 * 256 * 256;
    float* Y2 = X2 + (size_t)16 * 3 * 128 * 128;
    float* X3 = Y2 + (size_t)16 * 3 * 128 * 128;
    float* Y3 = X3 + (size_t)16 * 3 * 64 * 64;

    GaussW gw;
    {
        float s = 0.f;
        for (int i = 0; i < 11; ++i) {
            float d = (float)(i - 5);
            gw.g[i] = expf(-d * d / (2.f * 1.5f * 1.5f));
            s += gw.g[i];
        }
        for (int i = 0; i < 11; ++i) gw.g[i] /= s;
    }

    hipLaunchKernelGGL(init_acc_kernel, dim3((4 * NBIN * 16 + 255) / 256), dim3(256), 0, stream, P);

    hipLaunchKernelGGL(ssim_level_kernel, dim3(16, 16, 48), dim3(256), 0, stream,
                       X0, Y0, 512, gw, P + 0 * NBIN * 16, 0, X1, Y1);
    hipLaunchKernelGGL(ssim_level_kernel, dim3(8, 8, 48),   dim3(256), 0, stream,
                       X1, Y1, 256, gw, P + 1 * NBIN * 16, 0, X2, Y2);
    hipLaunchKernelGGL(ssim_level_kernel, dim3(4, 4, 48),   dim3(256), 0, stream,
                       X2, Y2, 128, gw, P + 2 * NBIN * 16, 0, X3, Y3);
    hipLaunchKernelGGL(ssim_level_kernel, dim3(2, 2, 48),   dim3(256), 0, stream,
                       X3, Y3, 64,  gw, P + 3 * NBIN * 16, 1, (float*)nullptr, (float*)nullptr);

    hipLaunchKernelGGL(finalize_kernel, dim3(1), dim3(256), 0, stream, P, out);
}